// Round 1
// baseline (250.558 us; speedup 1.0000x reference)
//
#include <hip/hip_runtime.h>

// ---------------------------------------------------------------------------
// CausalSelfAttention fused pipeline (MI355X / gfx950), round 0.
// f32 I/O per reference dtypes; bf16 MFMA compute internally (threshold 6.5e-2
// is bf16-floor level).
//
// Pipeline:
//   k_convert      : W{q,k,v,o} f32 -> bf16 in ws
//   k_rms_combine  : x0n=rmsnorm(x0); xm=0.5*(x+x0n) -> bf16; x -> bf16
//   k_gemm_qkv     : [q|k|v|v_init] = [xm|x] @ W^T  (M=4096, N=1792, K=1024)
//                    v_init panel written as f32 straight to d_out
//   k_qkv_post     : rope+rmsnorm*1.2 on q,k; v += 0.5*ve; -> head-major bf16
//   k_attn         : flash GQA sliding-window attention (16x16x32 bf16 MFMA)
//   k_gemm_o       : y = ao @ Wo^T -> f32 d_out
// ---------------------------------------------------------------------------

typedef __attribute__((ext_vector_type(8))) short bf16x8;
typedef __attribute__((ext_vector_type(4))) float f32x4;
typedef unsigned short u16;
typedef unsigned int u32;

#define B_ 2
#define T_ 2048
#define C_ 1024
#define NH_ 16
#define NKV_ 4
#define HD_ 64
#define WIN_ 1024
#define M_ (B_*T_)            // 4096 rows (b*T+t)
#define EPS_ 1.1920929e-07f

__device__ __forceinline__ u16 f2bf(float f) {
  u32 u = __float_as_uint(f);
  u32 r = (u + 0x7fffu + ((u >> 16) & 1u)) >> 16;
  return (u16)r;
}
__device__ __forceinline__ float bf2f(u16 h) { return __uint_as_float(((u32)h) << 16); }

// ---------------------------------------------------------------- convert W
__global__ __launch_bounds__(256) void k_convert(const float* __restrict__ src,
                                                 u16* __restrict__ dst, int n4) {
  int i = blockIdx.x * 256 + threadIdx.x;
  if (i >= n4) return;
  float4 v = ((const float4*)src)[i];
  ushort4 o;
  o.x = f2bf(v.x); o.y = f2bf(v.y); o.z = f2bf(v.z); o.w = f2bf(v.w);
  ((ushort4*)dst)[i] = o;
}

// ------------------------------------------------- rmsnorm(x0), xm, x->bf16
__global__ __launch_bounds__(256) void k_rms_combine(const float* __restrict__ x,
                                                     const float* __restrict__ x0,
                                                     u16* __restrict__ xbf,
                                                     u16* __restrict__ xmbf) {
  int row = blockIdx.x;
  int tid = threadIdx.x, lane = tid & 63, w = tid >> 6;
  const float4* px0 = (const float4*)(x0 + (size_t)row * C_);
  const float4* px  = (const float4*)(x  + (size_t)row * C_);
  float4 v0 = px0[tid];
  float ss = v0.x * v0.x + v0.y * v0.y + v0.z * v0.z + v0.w * v0.w;
  #pragma unroll
  for (int m = 1; m < 64; m <<= 1) ss += __shfl_xor(ss, m, 64);
  __shared__ float red[4];
  if (lane == 0) red[w] = ss;
  __syncthreads();
  float tot = red[0] + red[1] + red[2] + red[3];
  float rn = rsqrtf(tot * (1.0f / C_) + EPS_);
  float4 vx = px[tid];
  ushort4 om, ox;
  om.x = f2bf(0.5f * (vx.x + v0.x * rn));
  om.y = f2bf(0.5f * (vx.y + v0.y * rn));
  om.z = f2bf(0.5f * (vx.z + v0.z * rn));
  om.w = f2bf(0.5f * (vx.w + v0.w * rn));
  ox.x = f2bf(vx.x); ox.y = f2bf(vx.y); ox.z = f2bf(vx.z); ox.w = f2bf(vx.w);
  ((ushort4*)(xmbf + (size_t)row * C_))[tid] = om;
  ((ushort4*)(xbf  + (size_t)row * C_))[tid] = ox;
}

// ------------------------------------------------------------- GEMM core
// C[128 x 64] per block = A[128 x 1024] * W^T (W row-major [n][1024]).
// 4 waves, each 64x32 (acc[4][2] of 16x16 tiles). Register-staged LDS,
// padded stride 40 elems (80B: 16B-aligned b128, banks spread).
__device__ __forceinline__ void gemm_core(const u16* __restrict__ pa,
                                          const u16* __restrict__ pw,
                                          u16 (*As)[40], u16 (*Ws)[40],
                                          int lane, int r0, int c0,
                                          int ra, int ka, int rw, int kw,
                                          f32x4 acc[4][2]) {
  for (int kt = 0; kt < 1024; kt += 32) {
    int4 a0 = *(const int4*)(pa + kt);
    int4 a1 = *(const int4*)(pa + kt + 8);
    int4 w0 = *(const int4*)(pw + kt);
    __syncthreads();
    *(int4*)&As[ra][ka]     = a0;
    *(int4*)&As[ra][ka + 8] = a1;
    *(int4*)&Ws[rw][kw]     = w0;
    __syncthreads();
    bf16x8 af[4], bfr[2];
    #pragma unroll
    for (int fi = 0; fi < 4; fi++)
      af[fi] = *(const bf16x8*)&As[r0 + fi * 16 + (lane & 15)][(lane >> 4) * 8];
    #pragma unroll
    for (int fj = 0; fj < 2; fj++)
      bfr[fj] = *(const bf16x8*)&Ws[c0 + fj * 16 + (lane & 15)][(lane >> 4) * 8];
    #pragma unroll
    for (int fi = 0; fi < 4; fi++)
      #pragma unroll
      for (int fj = 0; fj < 2; fj++)
        acc[fi][fj] = __builtin_amdgcn_mfma_f32_16x16x32_bf16(af[fi], bfr[fj], acc[fi][fj], 0, 0, 0);
  }
}

// n-panels: bn 0-15 -> q (Wq, xm); 16-19 -> k (Wk, xm); 20-23 -> v (Wv, xm);
//           24-27 -> v_init (Wv, x) written f32 to d_out.
__global__ __launch_bounds__(256) void k_gemm_qkv(const u16* __restrict__ xm,
                                                  const u16* __restrict__ xb,
                                                  const u16* __restrict__ Wq,
                                                  const u16* __restrict__ Wk,
                                                  const u16* __restrict__ Wv,
                                                  u16* __restrict__ qpre,
                                                  u16* __restrict__ kpre,
                                                  u16* __restrict__ vmid,
                                                  float* __restrict__ vinit) {
  __shared__ u16 As[128][40];
  __shared__ u16 Ws[64][40];
  int tid = threadIdx.x, lane = tid & 63, w = tid >> 6;
  int m0 = blockIdx.x * 128, bn = blockIdx.y, n0 = bn * 64;
  const u16* A; const u16* Wseg; int nseg;
  if (bn < 16)      { A = xm; Wseg = Wq; nseg = n0; }
  else if (bn < 20) { A = xm; Wseg = Wk; nseg = n0 - 1024; }
  else if (bn < 24) { A = xm; Wseg = Wv; nseg = n0 - 1280; }
  else              { A = xb; Wseg = Wv; nseg = n0 - 1536; }
  int ra = tid >> 1, ka = (tid & 1) * 16;
  int rw = tid >> 2, kw = (tid & 3) * 8;
  const u16* pa = A + (size_t)(m0 + ra) * 1024 + ka;
  const u16* pw = Wseg + (size_t)(nseg + rw) * 1024 + kw;
  int r0 = (w >> 1) * 64, c0 = (w & 1) * 32;
  f32x4 acc[4][2] = {};
  gemm_core(pa, pw, As, Ws, lane, r0, c0, ra, ka, rw, kw, acc);
  #pragma unroll
  for (int fi = 0; fi < 4; fi++)
    #pragma unroll
    for (int fj = 0; fj < 2; fj++)
      #pragma unroll
      for (int i = 0; i < 4; i++) {
        int m = m0 + r0 + fi * 16 + (lane >> 4) * 4 + i;
        int nl = nseg + c0 + fj * 16 + (lane & 15);
        float v = acc[fi][fj][i];
        if (bn < 16)      qpre[(size_t)m * 1024 + nl] = f2bf(v);
        else if (bn < 20) kpre[(size_t)m * 256 + nl] = f2bf(v);
        else if (bn < 24) vmid[(size_t)m * 256 + nl] = f2bf(v);
        else              vinit[(size_t)m * 256 + nl] = v;
      }
}

__global__ __launch_bounds__(256) void k_gemm_o(const u16* __restrict__ A,
                                                const u16* __restrict__ W,
                                                float* __restrict__ y) {
  __shared__ u16 As[128][40];
  __shared__ u16 Ws[64][40];
  int tid = threadIdx.x, lane = tid & 63, w = tid >> 6;
  int m0 = blockIdx.x * 128, n0 = blockIdx.y * 64;
  int ra = tid >> 1, ka = (tid & 1) * 16;
  int rw = tid >> 2, kw = (tid & 3) * 8;
  const u16* pa = A + (size_t)(m0 + ra) * 1024 + ka;
  const u16* pw = W + (size_t)(n0 + rw) * 1024 + kw;
  int r0 = (w >> 1) * 64, c0 = (w & 1) * 32;
  f32x4 acc[4][2] = {};
  gemm_core(pa, pw, As, Ws, lane, r0, c0, ra, ka, rw, kw, acc);
  #pragma unroll
  for (int fi = 0; fi < 4; fi++)
    #pragma unroll
    for (int fj = 0; fj < 2; fj++)
      #pragma unroll
      for (int i = 0; i < 4; i++) {
        int m = m0 + r0 + fi * 16 + (lane >> 4) * 4 + i;
        int n = n0 + c0 + fj * 16 + (lane & 15);
        y[(size_t)m * 1024 + n] = acc[fi][fj][i];
      }
}

// ----------------------------------------- rope + rmsnorm*1.2, v += 0.5*ve
// One wave per 64-d head vector. vid order: q (B*T*NH), k (B*T*NKV), v.
__global__ __launch_bounds__(256) void k_qkv_post(const u16* __restrict__ qpre,
                                                  const u16* __restrict__ kpre,
                                                  const u16* __restrict__ vmid,
                                                  const float* __restrict__ ve,
                                                  const float* __restrict__ cosp,
                                                  const float* __restrict__ sinp,
                                                  u16* __restrict__ Qh,
                                                  u16* __restrict__ Kh,
                                                  u16* __restrict__ Vh) {
  int w = threadIdx.x >> 6, lane = threadIdx.x & 63;
  int vid = blockIdx.x * 4 + w;
  const int NQ = B_ * T_ * NH_;    // 65536
  const int NK = B_ * T_ * NKV_;   // 16384
  if (vid < NQ + NK) {
    int t, dstoff;
    float val;
    if (vid < NQ) {
      int h = vid & 15; t = (vid >> 4) & 2047; int b = vid >> 15;
      val = bf2f(qpre[(size_t)vid * 64 + lane]);
      dstoff = 0;
      // placeholder; dst computed below via branch
      size_t dst = (((size_t)(b * NH_ + h) * T_) + t) * 64 + lane;
      int di = lane & 31;
      float partner = __shfl_xor(val, 32, 64);
      float c = cosp[t * 32 + di], s = sinp[t * 32 + di];
      float r = (lane < 32) ? (val * c + partner * s) : (val * c - partner * s);
      float ss = r * r;
      #pragma unroll
      for (int m2 = 1; m2 < 64; m2 <<= 1) ss += __shfl_xor(ss, m2, 64);
      r *= rsqrtf(ss * (1.0f / 64.0f) + EPS_) * 1.2f;
      Qh[dst] = f2bf(r);
      (void)dstoff;
      return;
    } else {
      int kid = vid - NQ;
      int hk = kid & 3; t = (kid >> 2) & 2047; int b = kid >> 13;
      val = bf2f(kpre[(size_t)kid * 64 + lane]);
      size_t dst = (((size_t)(b * NKV_ + hk) * T_) + t) * 64 + lane;
      int di = lane & 31;
      float partner = __shfl_xor(val, 32, 64);
      float c = cosp[t * 32 + di], s = sinp[t * 32 + di];
      float r = (lane < 32) ? (val * c + partner * s) : (val * c - partner * s);
      float ss = r * r;
      #pragma unroll
      for (int m2 = 1; m2 < 64; m2 <<= 1) ss += __shfl_xor(ss, m2, 64);
      r *= rsqrtf(ss * (1.0f / 64.0f) + EPS_) * 1.2f;
      Kh[dst] = f2bf(r);
      return;
    }
  } else {
    int vvid = vid - NQ - NK;
    int hk = vvid & 3; int t = (vvid >> 2) & 2047; int b = vvid >> 13;
    float v = bf2f(vmid[(size_t)vvid * 64 + lane]) + 0.5f * ve[(size_t)vvid * 64 + lane];
    Vh[(((size_t)(b * NKV_ + hk) * T_) + t) * 64 + lane] = f2bf(v);
  }
}

// ---------------------------------------------------------------- attention
// Block = (qtile 64 rows, head, batch); 4 waves x 16 q-rows; KBLK=64 keys.
__global__ __launch_bounds__(256) void k_attn(const u16* __restrict__ Qh,
                                              const u16* __restrict__ Kh,
                                              const u16* __restrict__ Vh,
                                              u16* __restrict__ ao) {
  __shared__ u16 Ks[64][72];        // [key][d], stride 144B
  __shared__ u16 Vt[64][72];        // [d][key] (transposed), stride 144B
  __shared__ u16 Ps[4][16][72];     // per-wave P buffer [qrow][key]
  int tid = threadIdx.x, lane = tid & 63, w = tid >> 6;
  int qt = blockIdx.x, h = blockIdx.y, b = blockIdx.z;
  int hk = h >> 2;
  const u16* Qp = Qh + ((size_t)(b * NH_ + h) * T_) * 64;
  const u16* Kp = Kh + ((size_t)(b * NKV_ + hk) * T_) * 64;
  const u16* Vp = Vh + ((size_t)(b * NKV_ + hk) * T_) * 64;
  int q0 = qt * 64;
  int qr = q0 + w * 16 + (lane & 15);
  bf16x8 qf[2];
  qf[0] = *(const bf16x8*)(Qp + (size_t)qr * 64 + (lane >> 4) * 8);
  qf[1] = *(const bf16x8*)(Qp + (size_t)qr * 64 + 32 + (lane >> 4) * 8);
  f32x4 o[4] = {};
  float mrun[4], lrun[4];
  #pragma unroll
  for (int i = 0; i < 4; i++) { mrun[i] = -1e4f; lrun[i] = 0.f; }
  int kt_lo = q0 - WIN_; if (kt_lo < 0) kt_lo = 0;
  int rk = tid >> 2, dk = (tid & 3) * 16;     // K staging: 64 rows x 64 d
  int kp2 = tid >> 3, dv = (tid & 7) * 8;     // V staging: 32 key-pairs x 8 d
  for (int kt = kt_lo; kt <= q0; kt += 64) {
    int4 kv0 = *(const int4*)(Kp + (size_t)(kt + rk) * 64 + dk);
    int4 kv1 = *(const int4*)(Kp + (size_t)(kt + rk) * 64 + dk + 8);
    int4 va  = *(const int4*)(Vp + (size_t)(kt + 2 * kp2) * 64 + dv);
    int4 vb  = *(const int4*)(Vp + (size_t)(kt + 2 * kp2 + 1) * 64 + dv);
    __syncthreads();
    *(int4*)&Ks[rk][dk]     = kv0;
    *(int4*)&Ks[rk][dk + 8] = kv1;
    {
      const u16* sa = (const u16*)&va;
      const u16* sb = (const u16*)&vb;
      #pragma unroll
      for (int j = 0; j < 8; j++) {
        u32 valp = (u32)sa[j] | ((u32)sb[j] << 16);
        *(u32*)&Vt[dv + j][2 * kp2] = valp;
      }
    }
    __syncthreads();
    // S = Q K^T  (16 x 64 per wave)
    f32x4 s[4];
    #pragma unroll
    for (int ct = 0; ct < 4; ct++) {
      f32x4 z = {0.f, 0.f, 0.f, 0.f};
      s[ct] = z;
      #pragma unroll
      for (int kk = 0; kk < 2; kk++) {
        bf16x8 kf = *(const bf16x8*)&Ks[ct * 16 + (lane & 15)][kk * 32 + (lane >> 4) * 8];
        s[ct] = __builtin_amdgcn_mfma_f32_16x16x32_bf16(qf[kk], kf, s[ct], 0, 0, 0);
      }
    }
    // mask + scale + online softmax
    int irow_base = q0 + w * 16 + (lane >> 4) * 4;
    float tmax[4];
    #pragma unroll
    for (int i = 0; i < 4; i++) tmax[i] = -1e30f;
    #pragma unroll
    for (int ct = 0; ct < 4; ct++) {
      int j = kt + ct * 16 + (lane & 15);
      #pragma unroll
      for (int i = 0; i < 4; i++) {
        int irow = irow_base + i;
        bool valid = (j <= irow) && (irow - j <= WIN_);
        float sv = valid ? s[ct][i] * 0.125f : -1e9f;
        s[ct][i] = sv;
        tmax[i] = fmaxf(tmax[i], sv);
      }
    }
    #pragma unroll
    for (int i = 0; i < 4; i++) {
      #pragma unroll
      for (int m2 = 1; m2 < 16; m2 <<= 1) tmax[i] = fmaxf(tmax[i], __shfl_xor(tmax[i], m2, 64));
    }
    float alpha[4];
    #pragma unroll
    for (int i = 0; i < 4; i++) {
      float mn = fmaxf(mrun[i], tmax[i]);
      alpha[i] = __expf(mrun[i] - mn);
      mrun[i] = mn;
    }
    float rsum[4] = {0.f, 0.f, 0.f, 0.f};
    #pragma unroll
    for (int ct = 0; ct < 4; ct++)
      #pragma unroll
      for (int i = 0; i < 4; i++) {
        float p = __expf(s[ct][i] - mrun[i]);
        s[ct][i] = p;
        rsum[i] += p;
      }
    #pragma unroll
    for (int i = 0; i < 4; i++) {
      #pragma unroll
      for (int m2 = 1; m2 < 16; m2 <<= 1) rsum[i] += __shfl_xor(rsum[i], m2, 64);
      lrun[i] = lrun[i] * alpha[i] + rsum[i];
    }
    #pragma unroll
    for (int fj = 0; fj < 4; fj++)
      #pragma unroll
      for (int i = 0; i < 4; i++) o[fj][i] *= alpha[i];
    // P -> LDS (bf16), re-read in A-frag layout (wave-local, no barrier needed)
    #pragma unroll
    for (int ct = 0; ct < 4; ct++)
      #pragma unroll
      for (int i = 0; i < 4; i++)
        Ps[w][(lane >> 4) * 4 + i][ct * 16 + (lane & 15)] = f2bf(s[ct][i]);
    bf16x8 pf[2];
    pf[0] = *(const bf16x8*)&Ps[w][lane & 15][(lane >> 4) * 8];
    pf[1] = *(const bf16x8*)&Ps[w][lane & 15][32 + (lane >> 4) * 8];
    #pragma unroll
    for (int fj = 0; fj < 4; fj++) {
      #pragma unroll
      for (int ks = 0; ks < 2; ks++) {
        bf16x8 vf = *(const bf16x8*)&Vt[fj * 16 + (lane & 15)][ks * 32 + (lane >> 4) * 8];
        o[fj] = __builtin_amdgcn_mfma_f32_16x16x32_bf16(pf[ks], vf, o[fj], 0, 0, 0);
      }
    }
  }
  // normalize + store (b, t, h, d) bf16
  #pragma unroll
  for (int i = 0; i < 4; i++) {
    float inv = 1.0f / lrun[i];
    int irow = q0 + w * 16 + (lane >> 4) * 4 + i;
    size_t base = ((size_t)(b * T_ + irow) * NH_ + h) * 64;
    #pragma unroll
    for (int fj = 0; fj < 4; fj++)
      ao[base + fj * 16 + (lane & 15)] = f2bf(o[fj][i] * inv);
  }
}

// ---------------------------------------------------------------------------
extern "C" void kernel_launch(void* const* d_in, const int* in_sizes, int n_in,
                              void* d_out, int out_size, void* d_ws, size_t ws_size,
                              hipStream_t stream) {
  const float* x    = (const float*)d_in[0];
  const float* x0   = (const float*)d_in[1];
  const float* ve   = (const float*)d_in[2];
  const float* cosp = (const float*)d_in[3];
  const float* sinp = (const float*)d_in[4];
  const float* Wq   = (const float*)d_in[5];
  const float* Wk   = (const float*)d_in[6];
  const float* Wv   = (const float*)d_in[7];
  const float* Wo   = (const float*)d_in[8];
  float* out = (float*)d_out;                       // y [4194304] + v_init [1048576]

  // ws layout (bf16 elems). Aliased regions have disjoint lifetimes:
  //   ao  aliases xbf  (xbf last read in k_gemm_qkv; ao written in k_attn)
  //   Qh  aliases xmbf (xmbf last read in k_gemm_qkv; Qh written in k_qkv_post)
  //   Kh  aliases Wqb  (Wqb last read in k_gemm_qkv; Kh written in k_qkv_post)
  u16* ws = (u16*)d_ws;
  size_t off = 0;
  u16* xbf  = ws + off; off += (size_t)M_ * C_;       // 4,194,304  (also ao)
  u16* xmbf = ws + off; off += (size_t)M_ * C_;       // 4,194,304  (also Qh)
  u16* Wqb  = ws + off; off += (size_t)1024 * 1024;   // 1,048,576  (also Kh)
  u16* Wkb  = ws + off; off += (size_t)256 * 1024;
  u16* Wvb  = ws + off; off += (size_t)256 * 1024;
  u16* Wob  = ws + off; off += (size_t)1024 * 1024;
  u16* qpre = ws + off; off += (size_t)M_ * 1024;
  u16* kpre = ws + off; off += (size_t)M_ * 256;
  u16* vmid = ws + off; off += (size_t)M_ * 256;
  u16* Vhb  = ws + off; off += (size_t)B_ * NKV_ * T_ * 64;
  u16* aob = xbf;
  u16* Qhb = xmbf;
  u16* Khb = Wqb;
  // total ws use ~ 36.7 MB

  k_convert<<<1024, 256, 0, stream>>>(Wq, Wqb, 1024 * 1024 / 4);
  k_convert<<<256,  256, 0, stream>>>(Wk, Wkb, 256 * 1024 / 4);
  k_convert<<<256,  256, 0, stream>>>(Wv, Wvb, 256 * 1024 / 4);
  k_convert<<<1024, 256, 0, stream>>>(Wo, Wob, 1024 * 1024 / 4);
  k_rms_combine<<<4096, 256, 0, stream>>>(x, x0, xbf, xmbf);
  k_gemm_qkv<<<dim3(32, 28), 256, 0, stream>>>(xmbf, xbf, Wqb, Wkb, Wvb,
                                               qpre, kpre, vmid, out + (size_t)M_ * C_);
  k_qkv_post<<<24576, 256, 0, stream>>>(qpre, kpre, vmid, ve, cosp, sinp, Qhb, Khb, Vhb);
  k_attn<<<dim3(T_ / 64, NH_, B_), 256, 0, stream>>>(Qhb, Khb, Vhb, aob);
  k_gemm_o<<<dim3(32, 16), 256, 0, stream>>>(aob, Wob, out);
}

// Round 2
// 218.688 us; speedup vs baseline: 1.1457x; 1.1457x over previous
//
#include <hip/hip_runtime.h>

// ---------------------------------------------------------------------------
// CausalSelfAttention fused pipeline (MI355X / gfx950), round 2.
// Changes vs round 1:
//  - GEMMs: m97 structure (BK=64, global_load_lds w16, XOR-swizzled LDS reads
//    with pre-swizzled global source, linear LDS dest).
//  - Attention: V pre-transposed to [b][hk][d][t] global (k_vt), K and V^T
//    staged via global_load_lds (conflict-free), swizzled ds_read_b128 frags,
//    interior tiles skip mask arithmetic, longest-first block order.
//  - 4 weight-convert launches fused into 1.
// ---------------------------------------------------------------------------

typedef __attribute__((ext_vector_type(8))) short bf16x8;
typedef __attribute__((ext_vector_type(4))) float f32x4;
typedef unsigned short u16;
typedef unsigned int u32;

#define B_ 2
#define T_ 2048
#define C_ 1024
#define NH_ 16
#define NKV_ 4
#define WIN_ 1024
#define M_ (B_*T_)
#define EPS_ 1.1920929e-07f

__device__ __forceinline__ u16 f2bf(float f) {
  u32 u = __float_as_uint(f);
  u32 r = (u + 0x7fffu + ((u >> 16) & 1u)) >> 16;
  return (u16)r;
}
__device__ __forceinline__ float bf2f(u16 h) { return __uint_as_float(((u32)h) << 16); }

// global -> LDS direct DMA, 16B per lane. LDS dest = wave-uniform base + lane*16.
__device__ __forceinline__ void gload16(const u16* g, u16* l) {
  __builtin_amdgcn_global_load_lds((const __attribute__((address_space(1))) u32*)g,
                                   (__attribute__((address_space(3))) u32*)l, 16, 0, 0);
}
// byte offset of (row, kgroup-of-8-bf16) under the st-style XOR swizzle.
// Rows are 128B; spreading key = row&7.
#define SWZ(row, kg) ((((row)) << 7) + ((((kg) ^ ((row) & 7))) << 4))
// global k-offset (elems) a lane must fetch so that linear LDS slot (l>>3, l&7)
// holds the swizzled content.
#define SWO(lane) (8 * (((lane) & 7) ^ (((lane) >> 3) & 7)))

// ------------------------------------------------- fused f32->bf16 W convert
// dst = [Wqb|Wkb|Wvb|Wob] contiguous. Sizes in float4 units.
__global__ __launch_bounds__(256) void k_convert_all(const float* __restrict__ Wq,
                                                     const float* __restrict__ Wk,
                                                     const float* __restrict__ Wv,
                                                     const float* __restrict__ Wo,
                                                     u16* __restrict__ dst) {
  int i4 = blockIdx.x * 256 + threadIdx.x;   // 0 .. 655359
  const float* src; int s0;
  if (i4 < 262144)      { src = Wq; s0 = 0; }
  else if (i4 < 327680) { src = Wk; s0 = 262144; }
  else if (i4 < 393216) { src = Wv; s0 = 327680; }
  else                  { src = Wo; s0 = 393216; }
  float4 v = ((const float4*)src)[i4 - s0];
  ushort4 o;
  o.x = f2bf(v.x); o.y = f2bf(v.y); o.z = f2bf(v.z); o.w = f2bf(v.w);
  ((ushort4*)dst)[i4] = o;
}

// ------------------------------------------------- rmsnorm(x0), xm, x->bf16
__global__ __launch_bounds__(256) void k_rms_combine(const float* __restrict__ x,
                                                     const float* __restrict__ x0,
                                                     u16* __restrict__ xbf,
                                                     u16* __restrict__ xmbf) {
  int row = blockIdx.x;
  int tid = threadIdx.x, lane = tid & 63, w = tid >> 6;
  const float4* px0 = (const float4*)(x0 + (size_t)row * C_);
  const float4* px  = (const float4*)(x  + (size_t)row * C_);
  float4 v0 = px0[tid];
  float ss = v0.x * v0.x + v0.y * v0.y + v0.z * v0.z + v0.w * v0.w;
  #pragma unroll
  for (int m = 1; m < 64; m <<= 1) ss += __shfl_xor(ss, m, 64);
  __shared__ float red[4];
  if (lane == 0) red[w] = ss;
  __syncthreads();
  float tot = red[0] + red[1] + red[2] + red[3];
  float rn = rsqrtf(tot * (1.0f / C_) + EPS_);
  float4 vx = px[tid];
  ushort4 om, ox;
  om.x = f2bf(0.5f * (vx.x + v0.x * rn));
  om.y = f2bf(0.5f * (vx.y + v0.y * rn));
  om.z = f2bf(0.5f * (vx.z + v0.z * rn));
  om.w = f2bf(0.5f * (vx.w + v0.w * rn));
  ox.x = f2bf(vx.x); ox.y = f2bf(vx.y); ox.z = f2bf(vx.z); ox.w = f2bf(vx.w);
  ((ushort4*)(xmbf + (size_t)row * C_))[tid] = om;
  ((ushort4*)(xbf  + (size_t)row * C_))[tid] = ox;
}

// ------------------------------------------------------------- GEMM core
// 128x64 tile, BK=64, 4 waves each 64x32 (acc[4][2]). global_load_lds staging,
// swizzled ds_read_b128 frag loads. A [128][1024] bf16, W [n][1024] bf16.
__device__ __forceinline__ void gemm_core(const u16* pa0, const u16* pb0,
                                          u16* Asl, u16* Bsl,
                                          int lane, int w, int r0, int c0,
                                          f32x4 acc[4][2]) {
  const char* Ab = (const char*)Asl;
  const char* Bb = (const char*)Bsl;
  for (int kt = 0; kt < 1024; kt += 64) {
    __syncthreads();
    #pragma unroll
    for (int c = 0; c < 4; c++)
      gload16(pa0 + (size_t)c * 32 * 1024 + kt, Asl + (c * 32 + w * 8) * 64);
    #pragma unroll
    for (int c = 0; c < 2; c++)
      gload16(pb0 + (size_t)c * 32 * 1024 + kt, Bsl + (c * 32 + w * 8) * 64);
    __syncthreads();
    bf16x8 af[2][4], bfr[2][2];
    #pragma unroll
    for (int ks = 0; ks < 2; ks++) {
      #pragma unroll
      for (int fi = 0; fi < 4; fi++)
        af[ks][fi] = *(const bf16x8*)(Ab + SWZ(r0 + fi * 16 + (lane & 15), ks * 4 + (lane >> 4)));
      #pragma unroll
      for (int fj = 0; fj < 2; fj++)
        bfr[ks][fj] = *(const bf16x8*)(Bb + SWZ(c0 + fj * 16 + (lane & 15), ks * 4 + (lane >> 4)));
    }
    #pragma unroll
    for (int ks = 0; ks < 2; ks++)
      #pragma unroll
      for (int fi = 0; fi < 4; fi++)
        #pragma unroll
        for (int fj = 0; fj < 2; fj++)
          acc[fi][fj] = __builtin_amdgcn_mfma_f32_16x16x32_bf16(af[ks][fi], bfr[ks][fj], acc[fi][fj], 0, 0, 0);
  }
}

// n-panels (BN=64): bn 0-15 q (Wq,xm); 16-19 k (Wk,xm); 20-23 v (Wv,xm);
// 24-27 v_init (Wv,x) -> f32 d_out.
__global__ __launch_bounds__(256) void k_gemm_qkv(const u16* __restrict__ xm,
                                                  const u16* __restrict__ xb,
                                                  const u16* __restrict__ Wq,
                                                  const u16* __restrict__ Wk,
                                                  const u16* __restrict__ Wv,
                                                  u16* __restrict__ qpre,
                                                  u16* __restrict__ kpre,
                                                  u16* __restrict__ vmid,
                                                  float* __restrict__ vinit) {
  __shared__ u16 Asl[128 * 64];
  __shared__ u16 Bsl[64 * 64];
  int tid = threadIdx.x, lane = tid & 63, w = tid >> 6;
  int m0 = blockIdx.x * 128, bn = blockIdx.y, n0 = bn * 64;
  const u16* A; const u16* Wseg; int nseg;
  if (bn < 16)      { A = xm; Wseg = Wq; nseg = n0; }
  else if (bn < 20) { A = xm; Wseg = Wk; nseg = n0 - 1024; }
  else if (bn < 24) { A = xm; Wseg = Wv; nseg = n0 - 1280; }
  else              { A = xb; Wseg = Wv; nseg = n0 - 1536; }
  int swo = SWO(lane);
  const u16* pa0 = A    + (size_t)(m0 + w * 8 + (lane >> 3)) * 1024 + swo;
  const u16* pb0 = Wseg + (size_t)(nseg + w * 8 + (lane >> 3)) * 1024 + swo;
  int r0 = (w >> 1) * 64, c0 = (w & 1) * 32;
  f32x4 acc[4][2] = {};
  gemm_core(pa0, pb0, Asl, Bsl, lane, w, r0, c0, acc);
  #pragma unroll
  for (int fi = 0; fi < 4; fi++)
    #pragma unroll
    for (int fj = 0; fj < 2; fj++)
      #pragma unroll
      for (int i = 0; i < 4; i++) {
        int m = m0 + r0 + fi * 16 + (lane >> 4) * 4 + i;
        int nl = nseg + c0 + fj * 16 + (lane & 15);
        float v = acc[fi][fj][i];
        if (bn < 16)      qpre[(size_t)m * 1024 + nl] = f2bf(v);
        else if (bn < 20) kpre[(size_t)m * 256 + nl] = f2bf(v);
        else if (bn < 24) vmid[(size_t)m * 256 + nl] = f2bf(v);
        else              vinit[(size_t)m * 256 + nl] = v;
      }
}

__global__ __launch_bounds__(256) void k_gemm_o(const u16* __restrict__ A,
                                                const u16* __restrict__ W,
                                                float* __restrict__ y) {
  __shared__ u16 Asl[128 * 64];
  __shared__ u16 Bsl[64 * 64];
  int tid = threadIdx.x, lane = tid & 63, w = tid >> 6;
  int m0 = blockIdx.x * 128, n0 = blockIdx.y * 64;
  int swo = SWO(lane);
  const u16* pa0 = A + (size_t)(m0 + w * 8 + (lane >> 3)) * 1024 + swo;
  const u16* pb0 = W + (size_t)(n0 + w * 8 + (lane >> 3)) * 1024 + swo;
  int r0 = (w >> 1) * 64, c0 = (w & 1) * 32;
  f32x4 acc[4][2] = {};
  gemm_core(pa0, pb0, Asl, Bsl, lane, w, r0, c0, acc);
  #pragma unroll
  for (int fi = 0; fi < 4; fi++)
    #pragma unroll
    for (int fj = 0; fj < 2; fj++)
      #pragma unroll
      for (int i = 0; i < 4; i++) {
        int m = m0 + r0 + fi * 16 + (lane >> 4) * 4 + i;
        int n = n0 + c0 + fj * 16 + (lane & 15);
        y[(size_t)m * 1024 + n] = acc[fi][fj][i];
      }
}

// ----------------------------------------- rope + rmsnorm*1.2 on q,k heads
__global__ __launch_bounds__(256) void k_qk_post(const u16* __restrict__ qpre,
                                                 const u16* __restrict__ kpre,
                                                 const float* __restrict__ cosp,
                                                 const float* __restrict__ sinp,
                                                 u16* __restrict__ Qh,
                                                 u16* __restrict__ Kh) {
  int w = threadIdx.x >> 6, lane = threadIdx.x & 63;
  int vid = blockIdx.x * 4 + w;
  const int NQ = B_ * T_ * NH_;    // 65536
  int t; float val; size_t dst; u16* out;
  if (vid < NQ) {
    int h = vid & 15; t = (vid >> 4) & 2047; int b = vid >> 15;
    val = bf2f(qpre[(size_t)vid * 64 + lane]);
    dst = (((size_t)(b * NH_ + h) * T_) + t) * 64 + lane;
    out = Qh;
  } else {
    int kid = vid - NQ;
    int hk = kid & 3; t = (kid >> 2) & 2047; int b = kid >> 13;
    val = bf2f(kpre[(size_t)kid * 64 + lane]);
    dst = (((size_t)(b * NKV_ + hk) * T_) + t) * 64 + lane;
    out = Kh;
  }
  int di = lane & 31;
  float partner = __shfl_xor(val, 32, 64);
  float c = cosp[t * 32 + di], s = sinp[t * 32 + di];
  float r = (lane < 32) ? (val * c + partner * s) : (val * c - partner * s);
  float ss = r * r;
  #pragma unroll
  for (int m2 = 1; m2 < 64; m2 <<= 1) ss += __shfl_xor(ss, m2, 64);
  r *= rsqrtf(ss * (1.0f / 64.0f) + EPS_) * 1.2f;
  out[dst] = f2bf(r);
}

// --------------------------------- V: add 0.5*ve, transpose to [b][hk][d][t]
__global__ __launch_bounds__(256) void k_vt(const u16* __restrict__ vmid,
                                            const float* __restrict__ ve,
                                            u16* __restrict__ VtG) {
  __shared__ u16 S[64][72];
  int tid = threadIdx.x;
  int t0 = blockIdx.x * 64, hk = blockIdx.y, b = blockIdx.z;
  {
    int tl = tid >> 2, dg = (tid & 3) * 16;
    const int4* pvm = (const int4*)(vmid + (size_t)(b * T_ + t0 + tl) * 256 + hk * 64 + dg);
    const float4* pve = (const float4*)(ve + ((size_t)(b * T_ + t0 + tl) * 4 + hk) * 64 + dg);
    int4 vv[2]; vv[0] = pvm[0]; vv[1] = pvm[1];
    const u16* vm = (const u16*)vv;
    float4 vf[4]; vf[0] = pve[0]; vf[1] = pve[1]; vf[2] = pve[2]; vf[3] = pve[3];
    const float* vfp = (const float*)vf;
    u16 r[16];
    #pragma unroll
    for (int e = 0; e < 16; e++) r[e] = f2bf(bf2f(vm[e]) + 0.5f * vfp[e]);
    *(int4*)&S[tl][dg] = *(int4*)&r[0];
    *(int4*)&S[tl][dg + 8] = *(int4*)&r[8];
  }
  __syncthreads();
  {
    int dl = tid >> 2, tg = (tid & 3) * 16;
    u16 r[16];
    #pragma unroll
    for (int j = 0; j < 16; j++) r[j] = S[tg + j][dl];
    u16* o = VtG + ((size_t)((b * NKV_ + hk) * 64 + dl)) * T_ + t0 + tg;
    *(int4*)&o[0] = *(int4*)&r[0];
    *(int4*)&o[8] = *(int4*)&r[8];
  }
}

// ---------------------------------------------------------------- attention
// Block = (qtile 64 rows, head, batch), longest-first; 4 waves x 16 q-rows.
// K staged [key][d], V^T staged [d][key], both via global_load_lds + swizzle.
__global__ __launch_bounds__(256) void k_attn(const u16* __restrict__ Qh,
                                              const u16* __restrict__ Kh,
                                              const u16* __restrict__ VtG,
                                              u16* __restrict__ ao) {
  __shared__ u16 Ksl[64 * 64];
  __shared__ u16 Vsl[64 * 64];
  __shared__ u16 Ps[4][16][72];
  int tid = threadIdx.x, lane = tid & 63, w = tid >> 6;
  int qt = (int)gridDim.x - 1 - (int)blockIdx.x;   // longest-first
  int h = blockIdx.y, b = blockIdx.z;
  int hk = h >> 2;
  int q0 = qt * 64;
  const u16* Qp = Qh + ((size_t)(b * NH_ + h) * T_) * 64;
  const u16* Kp = Kh + ((size_t)(b * NKV_ + hk) * T_) * 64;
  int swo = SWO(lane);
  const u16* pk0 = Kp + (size_t)(w * 8 + (lane >> 3)) * 64 + swo;
  const u16* pv0 = VtG + ((size_t)((b * NKV_ + hk) * 64 + w * 8 + (lane >> 3))) * T_ + swo;
  const char* Kb = (const char*)Ksl;
  const char* Vb = (const char*)Vsl;

  int qr = q0 + w * 16 + (lane & 15);
  bf16x8 qf[2];
  qf[0] = *(const bf16x8*)(Qp + (size_t)qr * 64 + (lane >> 4) * 8);
  qf[1] = *(const bf16x8*)(Qp + (size_t)qr * 64 + 32 + (lane >> 4) * 8);

  f32x4 o[4] = {};
  float mrun[4], lrun[4];
  #pragma unroll
  for (int i = 0; i < 4; i++) { mrun[i] = -1e4f; lrun[i] = 0.f; }
  int kt_lo = q0 - WIN_; if (kt_lo < 0) kt_lo = 0;

  for (int kt = kt_lo; kt <= q0; kt += 64) {
    __syncthreads();
    #pragma unroll
    for (int c = 0; c < 2; c++) {
      gload16(pk0 + (size_t)(kt + c * 32) * 64, Ksl + (c * 32 + w * 8) * 64);
      gload16(pv0 + kt + (size_t)c * 32 * T_,   Vsl + (c * 32 + w * 8) * 64);
    }
    __syncthreads();
    // S = Q K^T (16 x 64 per wave)
    f32x4 s[4];
    #pragma unroll
    for (int ct = 0; ct < 4; ct++) {
      f32x4 z = {0.f, 0.f, 0.f, 0.f};
      s[ct] = z;
      #pragma unroll
      for (int ks = 0; ks < 2; ks++) {
        bf16x8 kf = *(const bf16x8*)(Kb + SWZ(ct * 16 + (lane & 15), ks * 4 + (lane >> 4)));
        s[ct] = __builtin_amdgcn_mfma_f32_16x16x32_bf16(qf[ks], kf, s[ct], 0, 0, 0);
      }
    }
    // scale (+ mask only on boundary tiles) + online softmax
    bool need_mask = (kt == q0) || (kt == q0 - WIN_);
    int irow0 = q0 + w * 16 + (lane >> 4) * 4;
    float tmax[4] = {-1e30f, -1e30f, -1e30f, -1e30f};
    if (need_mask) {
      #pragma unroll
      for (int ct = 0; ct < 4; ct++) {
        int j = kt + ct * 16 + (lane & 15);
        #pragma unroll
        for (int i = 0; i < 4; i++) {
          int irow = irow0 + i;
          bool valid = (j <= irow) && (irow - j <= WIN_);
          float sv = valid ? s[ct][i] * 0.125f : -1e9f;
          s[ct][i] = sv;
          tmax[i] = fmaxf(tmax[i], sv);
        }
      }
    } else {
      #pragma unroll
      for (int ct = 0; ct < 4; ct++)
        #pragma unroll
        for (int i = 0; i < 4; i++) {
          float sv = s[ct][i] * 0.125f;
          s[ct][i] = sv;
          tmax[i] = fmaxf(tmax[i], sv);
        }
    }
    #pragma unroll
    for (int i = 0; i < 4; i++) {
      #pragma unroll
      for (int m2 = 1; m2 < 16; m2 <<= 1) tmax[i] = fmaxf(tmax[i], __shfl_xor(tmax[i], m2, 64));
    }
    float alpha[4];
    #pragma unroll
    for (int i = 0; i < 4; i++) {
      float mn = fmaxf(mrun[i], tmax[i]);
      alpha[i] = __expf(mrun[i] - mn);
      mrun[i] = mn;
    }
    float rsum[4] = {0.f, 0.f, 0.f, 0.f};
    #pragma unroll
    for (int ct = 0; ct < 4; ct++)
      #pragma unroll
      for (int i = 0; i < 4; i++) {
        float p = __expf(s[ct][i] - mrun[i]);
        s[ct][i] = p;
        rsum[i] += p;
      }
    #pragma unroll
    for (int i = 0; i < 4; i++) {
      #pragma unroll
      for (int m2 = 1; m2 < 16; m2 <<= 1) rsum[i] += __shfl_xor(rsum[i], m2, 64);
      lrun[i] = lrun[i] * alpha[i] + rsum[i];
    }
    #pragma unroll
    for (int fj = 0; fj < 4; fj++)
      #pragma unroll
      for (int i = 0; i < 4; i++) o[fj][i] *= alpha[i];
    // P -> LDS (bf16), wave-local round trip into A-frag layout
    #pragma unroll
    for (int ct = 0; ct < 4; ct++)
      #pragma unroll
      for (int i = 0; i < 4; i++)
        Ps[w][(lane >> 4) * 4 + i][ct * 16 + (lane & 15)] = f2bf(s[ct][i]);
    bf16x8 pf[2];
    pf[0] = *(const bf16x8*)&Ps[w][lane & 15][(lane >> 4) * 8];
    pf[1] = *(const bf16x8*)&Ps[w][lane & 15][32 + (lane >> 4) * 8];
    #pragma unroll
    for (int fj = 0; fj < 4; fj++) {
      #pragma unroll
      for (int ks = 0; ks < 2; ks++) {
        bf16x8 vf = *(const bf16x8*)(Vb + SWZ(fj * 16 + (lane & 15), ks * 4 + (lane >> 4)));
        o[fj] = __builtin_amdgcn_mfma_f32_16x16x32_bf16(pf[ks], vf, o[fj], 0, 0, 0);
      }
    }
  }
  // normalize + store (b, t, h, d) bf16
  #pragma unroll
  for (int i = 0; i < 4; i++) {
    float inv = 1.0f / lrun[i];
    int irow = q0 + w * 16 + (lane >> 4) * 4 + i;
    size_t base = ((size_t)(b * T_ + irow) * NH_ + h) * 64;
    #pragma unroll
    for (int fj = 0; fj < 4; fj++)
      ao[base + fj * 16 + (lane & 15)] = f2bf(o[fj][i] * inv);
  }
}

// ---------------------------------------------------------------------------
extern "C" void kernel_launch(void* const* d_in, const int* in_sizes, int n_in,
                              void* d_out, int out_size, void* d_ws, size_t ws_size,
                              hipStream_t stream) {
  const float* x    = (const float*)d_in[0];
  const float* x0   = (const float*)d_in[1];
  const float* ve   = (const float*)d_in[2];
  const float* cosp = (const float*)d_in[3];
  const float* sinp = (const float*)d_in[4];
  const float* Wq   = (const float*)d_in[5];
  const float* Wk   = (const float*)d_in[6];
  const float* Wv   = (const float*)d_in[7];
  const float* Wo   = (const float*)d_in[8];
  float* out = (float*)d_out;                 // y [4194304] + v_init [1048576]

  // ws layout (bf16 elems). Aliases have disjoint lifetimes:
  //   ao aliases xbf; Qh aliases xmbf; Kh aliases Wqb.
  u16* ws = (u16*)d_ws;
  size_t off = 0;
  u16* xbf  = ws + off; off += (size_t)M_ * C_;       // also ao
  u16* xmbf = ws + off; off += (size_t)M_ * C_;       // also Qh
  u16* Wqb  = ws + off; off += (size_t)1024 * 1024;   // also Kh
  u16* Wkb  = ws + off; off += (size_t)256 * 1024;
  u16* Wvb  = ws + off; off += (size_t)256 * 1024;
  u16* Wob  = ws + off; off += (size_t)1024 * 1024;
  u16* qpre = ws + off; off += (size_t)M_ * 1024;
  u16* kpre = ws + off; off += (size_t)M_ * 256;
  u16* vmid = ws + off; off += (size_t)M_ * 256;
  u16* VtG  = ws + off; off += (size_t)B_ * NKV_ * 64 * T_;
  u16* aob = xbf;
  u16* Qhb = xmbf;
  u16* Khb = Wqb;

  k_convert_all<<<2560, 256, 0, stream>>>(Wq, Wk, Wv, Wo, Wqb);
  k_rms_combine<<<4096, 256, 0, stream>>>(x, x0, xbf, xmbf);
  k_gemm_qkv<<<dim3(32, 28), 256, 0, stream>>>(xmbf, xbf, Wqb, Wkb, Wvb,
                                               qpre, kpre, vmid, out + (size_t)M_ * C_);
  k_qk_post<<<20480, 256, 0, stream>>>(qpre, kpre, cosp, sinp, Qhb, Khb);
  k_vt<<<dim3(32, 4, 2), 256, 0, stream>>>(vmid, ve, VtG);
  k_attn<<<dim3(32, 16, 2), 256, 0, stream>>>(Qhb, Khb, VtG, aob);
  k_gemm_o<<<dim3(32, 16), 256, 0, stream>>>(aob, Wob, out);
}

// Round 3
// 214.171 us; speedup vs baseline: 1.1699x; 1.0211x over previous
//
#include <hip/hip_runtime.h>

// ---------------------------------------------------------------------------
// CausalSelfAttention fused pipeline (MI355X / gfx950), round 3.
// Changes vs round 2:
//  - k_attn rewritten: 8-wave 32x32 swapped-QK^T (S^T = mfma(K,Q)) so softmax
//    is lane-local; in-register P->A-frag via v_perm pack + shfl_xor(32);
//    defer-max rescale (THR=8); double-buffered LDS, 1 barrier/tile;
//    per-warp tile skip. Scale (1.2*0.125) folded into Q at k_qk_post.
//  - GEMM cores: double-buffered LDS, 1 barrier per K-step.
// ---------------------------------------------------------------------------

typedef __attribute__((ext_vector_type(8))) short bf16x8;
typedef __attribute__((ext_vector_type(4))) float f32x4;
typedef __attribute__((ext_vector_type(16))) float f32x16;
typedef unsigned short u16;
typedef unsigned int u32;

#define B_ 2
#define T_ 2048
#define C_ 1024
#define NH_ 16
#define NKV_ 4
#define WIN_ 1024
#define M_ (B_*T_)
#define EPS_ 1.1920929e-07f

__device__ __forceinline__ u16 f2bf(float f) {
  u32 u = __float_as_uint(f);
  u32 r = (u + 0x7fffu + ((u >> 16) & 1u)) >> 16;
  return (u16)r;
}
__device__ __forceinline__ float bf2f(u16 h) { return __uint_as_float(((u32)h) << 16); }

__device__ __forceinline__ void gload16(const u16* g, u16* l) {
  __builtin_amdgcn_global_load_lds((const __attribute__((address_space(1))) u32*)g,
                                   (__attribute__((address_space(3))) u32*)l, 16, 0, 0);
}
// byte offset of (row, kgroup-of-8-bf16) under the XOR swizzle; rows are 128B.
#define SWZ(row, kg) ((((row)) << 7) + ((((kg) ^ ((row) & 7))) << 4))
// global elem offset a lane fetches so linear LDS slot (l>>3, l&7) holds swz content
#define SWO(lane) (8 * (((lane) & 7) ^ (((lane) >> 3) & 7)))

// ------------------------------------------------- fused f32->bf16 W convert
__global__ __launch_bounds__(256) void k_convert_all(const float* __restrict__ Wq,
                                                     const float* __restrict__ Wk,
                                                     const float* __restrict__ Wv,
                                                     const float* __restrict__ Wo,
                                                     u16* __restrict__ dst) {
  int i4 = blockIdx.x * 256 + threadIdx.x;
  const float* src; int s0;
  if (i4 < 262144)      { src = Wq; s0 = 0; }
  else if (i4 < 327680) { src = Wk; s0 = 262144; }
  else if (i4 < 393216) { src = Wv; s0 = 327680; }
  else                  { src = Wo; s0 = 393216; }
  float4 v = ((const float4*)src)[i4 - s0];
  ushort4 o;
  o.x = f2bf(v.x); o.y = f2bf(v.y); o.z = f2bf(v.z); o.w = f2bf(v.w);
  ((ushort4*)dst)[i4] = o;
}

// ------------------------------------------------- rmsnorm(x0), xm, x->bf16
__global__ __launch_bounds__(256) void k_rms_combine(const float* __restrict__ x,
                                                     const float* __restrict__ x0,
                                                     u16* __restrict__ xbf,
                                                     u16* __restrict__ xmbf) {
  int row = blockIdx.x;
  int tid = threadIdx.x, lane = tid & 63, w = tid >> 6;
  const float4* px0 = (const float4*)(x0 + (size_t)row * C_);
  const float4* px  = (const float4*)(x  + (size_t)row * C_);
  float4 v0 = px0[tid];
  float ss = v0.x * v0.x + v0.y * v0.y + v0.z * v0.z + v0.w * v0.w;
  #pragma unroll
  for (int m = 1; m < 64; m <<= 1) ss += __shfl_xor(ss, m, 64);
  __shared__ float red[4];
  if (lane == 0) red[w] = ss;
  __syncthreads();
  float tot = red[0] + red[1] + red[2] + red[3];
  float rn = rsqrtf(tot * (1.0f / C_) + EPS_);
  float4 vx = px[tid];
  ushort4 om, ox;
  om.x = f2bf(0.5f * (vx.x + v0.x * rn));
  om.y = f2bf(0.5f * (vx.y + v0.y * rn));
  om.z = f2bf(0.5f * (vx.z + v0.z * rn));
  om.w = f2bf(0.5f * (vx.w + v0.w * rn));
  ox.x = f2bf(vx.x); ox.y = f2bf(vx.y); ox.z = f2bf(vx.z); ox.w = f2bf(vx.w);
  ((ushort4*)(xmbf + (size_t)row * C_))[tid] = om;
  ((ushort4*)(xbf  + (size_t)row * C_))[tid] = ox;
}

// ------------------------------------------------------------- GEMM core
// 128x64 tile, BK=64, double-buffered LDS, 1 barrier per K-step.
__device__ __forceinline__ void gemm_core(const u16* pa0, const u16* pb0,
                                          u16* Asl, u16* Bsl,
                                          int lane, int w, int r0, int c0,
                                          f32x4 acc[4][2]) {
  #pragma unroll
  for (int c = 0; c < 4; c++) gload16(pa0 + (size_t)c * 32 * 1024, Asl + (c * 32 + w * 8) * 64);
  #pragma unroll
  for (int c = 0; c < 2; c++) gload16(pb0 + (size_t)c * 32 * 1024, Bsl + (c * 32 + w * 8) * 64);
  int cur = 0;
  for (int kt = 0; kt < 1024; kt += 64) {
    __syncthreads();
    if (kt + 64 < 1024) {
      int nxt = cur ^ 1;
      #pragma unroll
      for (int c = 0; c < 4; c++)
        gload16(pa0 + (size_t)c * 32 * 1024 + kt + 64, Asl + nxt * 8192 + (c * 32 + w * 8) * 64);
      #pragma unroll
      for (int c = 0; c < 2; c++)
        gload16(pb0 + (size_t)c * 32 * 1024 + kt + 64, Bsl + nxt * 4096 + (c * 32 + w * 8) * 64);
    }
    const char* Ab = (const char*)(Asl + cur * 8192);
    const char* Bb = (const char*)(Bsl + cur * 4096);
    bf16x8 af[2][4], bfr[2][2];
    #pragma unroll
    for (int ks = 0; ks < 2; ks++) {
      #pragma unroll
      for (int fi = 0; fi < 4; fi++)
        af[ks][fi] = *(const bf16x8*)(Ab + SWZ(r0 + fi * 16 + (lane & 15), ks * 4 + (lane >> 4)));
      #pragma unroll
      for (int fj = 0; fj < 2; fj++)
        bfr[ks][fj] = *(const bf16x8*)(Bb + SWZ(c0 + fj * 16 + (lane & 15), ks * 4 + (lane >> 4)));
    }
    #pragma unroll
    for (int ks = 0; ks < 2; ks++)
      #pragma unroll
      for (int fi = 0; fi < 4; fi++)
        #pragma unroll
        for (int fj = 0; fj < 2; fj++)
          acc[fi][fj] = __builtin_amdgcn_mfma_f32_16x16x32_bf16(af[ks][fi], bfr[ks][fj], acc[fi][fj], 0, 0, 0);
    cur ^= 1;
  }
}

__global__ __launch_bounds__(256) void k_gemm_qkv(const u16* __restrict__ xm,
                                                  const u16* __restrict__ xb,
                                                  const u16* __restrict__ Wq,
                                                  const u16* __restrict__ Wk,
                                                  const u16* __restrict__ Wv,
                                                  u16* __restrict__ qpre,
                                                  u16* __restrict__ kpre,
                                                  u16* __restrict__ vmid,
                                                  float* __restrict__ vinit) {
  __shared__ u16 Asl[2 * 8192];
  __shared__ u16 Bsl[2 * 4096];
  int tid = threadIdx.x, lane = tid & 63, w = tid >> 6;
  int m0 = blockIdx.x * 128, bn = blockIdx.y, n0 = bn * 64;
  const u16* A; const u16* Wseg; int nseg;
  if (bn < 16)      { A = xm; Wseg = Wq; nseg = n0; }
  else if (bn < 20) { A = xm; Wseg = Wk; nseg = n0 - 1024; }
  else if (bn < 24) { A = xm; Wseg = Wv; nseg = n0 - 1280; }
  else              { A = xb; Wseg = Wv; nseg = n0 - 1536; }
  int swo = SWO(lane);
  const u16* pa0 = A    + (size_t)(m0 + w * 8 + (lane >> 3)) * 1024 + swo;
  const u16* pb0 = Wseg + (size_t)(nseg + w * 8 + (lane >> 3)) * 1024 + swo;
  int r0 = (w >> 1) * 64, c0 = (w & 1) * 32;
  f32x4 acc[4][2] = {};
  gemm_core(pa0, pb0, Asl, Bsl, lane, w, r0, c0, acc);
  #pragma unroll
  for (int fi = 0; fi < 4; fi++)
    #pragma unroll
    for (int fj = 0; fj < 2; fj++)
      #pragma unroll
      for (int i = 0; i < 4; i++) {
        int m = m0 + r0 + fi * 16 + (lane >> 4) * 4 + i;
        int nl = nseg + c0 + fj * 16 + (lane & 15);
        float v = acc[fi][fj][i];
        if (bn < 16)      qpre[(size_t)m * 1024 + nl] = f2bf(v);
        else if (bn < 20) kpre[(size_t)m * 256 + nl] = f2bf(v);
        else if (bn < 24) vmid[(size_t)m * 256 + nl] = f2bf(v);
        else              vinit[(size_t)m * 256 + nl] = v;
      }
}

__global__ __launch_bounds__(256) void k_gemm_o(const u16* __restrict__ A,
                                                const u16* __restrict__ W,
                                                float* __restrict__ y) {
  __shared__ u16 Asl[2 * 8192];
  __shared__ u16 Bsl[2 * 4096];
  int tid = threadIdx.x, lane = tid & 63, w = tid >> 6;
  int m0 = blockIdx.x * 128, n0 = blockIdx.y * 64;
  int swo = SWO(lane);
  const u16* pa0 = A + (size_t)(m0 + w * 8 + (lane >> 3)) * 1024 + swo;
  const u16* pb0 = W + (size_t)(n0 + w * 8 + (lane >> 3)) * 1024 + swo;
  int r0 = (w >> 1) * 64, c0 = (w & 1) * 32;
  f32x4 acc[4][2] = {};
  gemm_core(pa0, pb0, Asl, Bsl, lane, w, r0, c0, acc);
  #pragma unroll
  for (int fi = 0; fi < 4; fi++)
    #pragma unroll
    for (int fj = 0; fj < 2; fj++)
      #pragma unroll
      for (int i = 0; i < 4; i++) {
        int m = m0 + r0 + fi * 16 + (lane >> 4) * 4 + i;
        int n = n0 + c0 + fj * 16 + (lane & 15);
        y[(size_t)m * 1024 + n] = acc[fi][fj][i];
      }
}

// ----------------------------------------- rope + rmsnorm on q,k heads
// Q gets full attention scale folded in: 1.2 * (1/8) = 0.15. K gets 1.2.
__global__ __launch_bounds__(256) void k_qk_post(const u16* __restrict__ qpre,
                                                 const u16* __restrict__ kpre,
                                                 const float* __restrict__ cosp,
                                                 const float* __restrict__ sinp,
                                                 u16* __restrict__ Qh,
                                                 u16* __restrict__ Kh) {
  int w = threadIdx.x >> 6, lane = threadIdx.x & 63;
  int vid = blockIdx.x * 4 + w;
  const int NQ = B_ * T_ * NH_;
  int t; float val; size_t dst; u16* out; float scale;
  if (vid < NQ) {
    int h = vid & 15; t = (vid >> 4) & 2047; int b = vid >> 15;
    val = bf2f(qpre[(size_t)vid * 64 + lane]);
    dst = (((size_t)(b * NH_ + h) * T_) + t) * 64 + lane;
    out = Qh; scale = 0.15f;
  } else {
    int kid = vid - NQ;
    int hk = kid & 3; t = (kid >> 2) & 2047; int b = kid >> 13;
    val = bf2f(kpre[(size_t)kid * 64 + lane]);
    dst = (((size_t)(b * NKV_ + hk) * T_) + t) * 64 + lane;
    out = Kh; scale = 1.2f;
  }
  int di = lane & 31;
  float partner = __shfl_xor(val, 32, 64);
  float c = cosp[t * 32 + di], s = sinp[t * 32 + di];
  float r = (lane < 32) ? (val * c + partner * s) : (val * c - partner * s);
  float ss = r * r;
  #pragma unroll
  for (int m2 = 1; m2 < 64; m2 <<= 1) ss += __shfl_xor(ss, m2, 64);
  r *= rsqrtf(ss * (1.0f / 64.0f) + EPS_) * scale;
  out[dst] = f2bf(r);
}

// --------------------------------- V: add 0.5*ve, transpose to [b][hk][d][t]
__global__ __launch_bounds__(256) void k_vt(const u16* __restrict__ vmid,
                                            const float* __restrict__ ve,
                                            u16* __restrict__ VtG) {
  __shared__ u16 S[64][72];
  int tid = threadIdx.x;
  int t0 = blockIdx.x * 64, hk = blockIdx.y, b = blockIdx.z;
  {
    int tl = tid >> 2, dg = (tid & 3) * 16;
    const int4* pvm = (const int4*)(vmid + (size_t)(b * T_ + t0 + tl) * 256 + hk * 64 + dg);
    const float4* pve = (const float4*)(ve + ((size_t)(b * T_ + t0 + tl) * 4 + hk) * 64 + dg);
    int4 vv[2]; vv[0] = pvm[0]; vv[1] = pvm[1];
    const u16* vm = (const u16*)vv;
    float4 vf[4]; vf[0] = pve[0]; vf[1] = pve[1]; vf[2] = pve[2]; vf[3] = pve[3];
    const float* vfp = (const float*)vf;
    u16 r[16];
    #pragma unroll
    for (int e = 0; e < 16; e++) r[e] = f2bf(bf2f(vm[e]) + 0.5f * vfp[e]);
    *(int4*)&S[tl][dg] = *(int4*)&r[0];
    *(int4*)&S[tl][dg + 8] = *(int4*)&r[8];
  }
  __syncthreads();
  {
    int dl = tid >> 2, tg = (tid & 3) * 16;
    u16 r[16];
    #pragma unroll
    for (int j = 0; j < 16; j++) r[j] = S[tg + j][dl];
    u16* o = VtG + ((size_t)((b * NKV_ + hk) * 64 + dl)) * T_ + t0 + tg;
    *(int4*)&o[0] = *(int4*)&r[0];
    *(int4*)&o[8] = *(int4*)&r[8];
  }
}

// ---------------------------------------------------------------- attention
// 8 waves x 32 q-rows = 256 q per block; KVBLK=64; swapped QK^T (S^T=K*Q) so
// each lane owns one q column; softmax lane-local + 1 shfl_xor(32).
// P->A-frag in registers (v_perm RTZ pack + shfl_xor(32)); defer-max rescale.
__global__ __launch_bounds__(512) void k_attn(const u16* __restrict__ Qh,
                                              const u16* __restrict__ Kh,
                                              const u16* __restrict__ VtG,
                                              u16* __restrict__ ao) {
  __shared__ u16 Ksl[2][64 * 64];
  __shared__ u16 Vsl[2][64 * 64];
  __shared__ float Sc[8][32];
  int tid = threadIdx.x, lane = tid & 63, w = tid >> 6;
  int hi = lane >> 5, qc = lane & 31;
  int qt = blockIdx.x, h = blockIdx.y, b = blockIdx.z;
  int hk = h >> 2;
  int q0 = qt * 256, wq0 = q0 + w * 32;
  const u16* Qp = Qh + ((size_t)(b * NH_ + h) * T_) * 64;
  const u16* Kp = Kh + ((size_t)(b * NKV_ + hk) * T_) * 64;
  int swo = SWO(lane);
  const u16* pk0 = Kp + (size_t)(w * 8 + (lane >> 3)) * 64 + swo;
  const u16* pv0 = VtG + ((size_t)((b * NKV_ + hk) * 64 + w * 8 + (lane >> 3))) * T_ + swo;

  // Q fragments (B-operand): qf[ds][j] = Q[wq0+qc][16*ds + 8*hi + j]
  bf16x8 qf[4];
  #pragma unroll
  for (int ds = 0; ds < 4; ds++)
    qf[ds] = *(const bf16x8*)(Qp + (size_t)(wq0 + qc) * 64 + ds * 16 + hi * 8);

  f32x16 o0 = {}, o1 = {};
  float mrun = -1e4f, lrun = 0.f;
  int kt_lo = q0 - WIN_; if (kt_lo < 0) kt_lo = 0;
  int kt_hi = q0 + 192;

  gload16(pk0 + (size_t)kt_lo * 64, &Ksl[0][w * 512]);
  gload16(pv0 + kt_lo,              &Vsl[0][w * 512]);
  int cur = 0;
  for (int kt = kt_lo; kt <= kt_hi; kt += 64) {
    __syncthreads();                       // buf[cur] staged (vmcnt drained)
    if (kt + 64 <= kt_hi) {                // async prefetch next tile
      gload16(pk0 + (size_t)(kt + 64) * 64, &Ksl[cur ^ 1][w * 512]);
      gload16(pv0 + kt + 64,                &Vsl[cur ^ 1][w * 512]);
    }
    if (kt <= wq0 + 31 && kt + 63 >= wq0 - WIN_) {
      const char* Kb = (const char*)&Ksl[cur][0];
      const char* Vb = (const char*)&Vsl[cur][0];
      // S^T[key][q] = K * Q : per lane 32 keys for q = qc
      f32x16 st[2] = {};
      #pragma unroll
      for (int kt2 = 0; kt2 < 2; kt2++)
        #pragma unroll
        for (int ds = 0; ds < 4; ds++) {
          bf16x8 kf = *(const bf16x8*)(Kb + SWZ(kt2 * 32 + qc, 2 * ds + hi));
          st[kt2] = __builtin_amdgcn_mfma_f32_32x32x16_bf16(kf, qf[ds], st[kt2], 0, 0, 0);
        }
      // mask (boundary tiles only) + tile max
      bool full = (kt + 63 <= wq0) && (wq0 + 31 - kt <= WIN_);
      int D0 = wq0 + qc - kt;
      float p[2][16];
      float tmax = -1e30f;
      #pragma unroll
      for (int kt2 = 0; kt2 < 2; kt2++)
        #pragma unroll
        for (int r = 0; r < 16; r++) {
          float sv = st[kt2][r];
          if (!full) {
            int jl = 32 * kt2 + (r & 3) + 8 * (r >> 2) + 4 * hi;
            sv = (jl <= D0 && jl >= D0 - WIN_) ? sv : -1e9f;
          }
          p[kt2][r] = sv;
          tmax = fmaxf(tmax, sv);
        }
      tmax = fmaxf(tmax, __shfl_xor(tmax, 32, 64));
      // defer-max rescale
      if (__any(tmax > mrun + 8.0f)) {
        float mnew = fmaxf(mrun, tmax);
        float alpha = __expf(mrun - mnew);
        mrun = mnew; lrun *= alpha;
        if (hi == 0) Sc[w][qc] = alpha;
        #pragma unroll
        for (int r = 0; r < 16; r++) {
          float al = Sc[w][(r & 3) + 8 * (r >> 2) + 4 * hi];
          o0[r] *= al; o1[r] *= al;
        }
      }
      // exp + RTZ bf16 pack (v_perm) + row sum
      float rsum = 0.f;
      u32 pw[2][8];
      #pragma unroll
      for (int kt2 = 0; kt2 < 2; kt2++)
        #pragma unroll
        for (int c = 0; c < 8; c++) {
          float pe = __expf(p[kt2][2 * c] - mrun);
          float po = __expf(p[kt2][2 * c + 1] - mrun);
          rsum += pe + po;
          pw[kt2][c] = __builtin_amdgcn_perm(__float_as_uint(po), __float_as_uint(pe), 0x07060302u);
        }
      rsum += __shfl_xor(rsum, 32, 64);
      lrun += rsum;
      // P A-frags via cross-half exchange, then PV
      #pragma unroll
      for (int kt2 = 0; kt2 < 2; kt2++)
        #pragma unroll
        for (int ksp = 0; ksp < 2; ksp++) {
          union { u32 uw[4]; bf16x8 v; } U;
          #pragma unroll
          for (int c = 0; c < 2; c++) {
            u32 x = pw[kt2][4 * ksp + c];
            u32 y = pw[kt2][4 * ksp + 2 + c];
            u32 xs = (u32)__shfl_xor((int)x, 32, 64);
            u32 ys = (u32)__shfl_xor((int)y, 32, 64);
            U.uw[c]     = hi ? ys : x;
            U.uw[2 + c] = hi ? y : xs;
          }
          int ks = 2 * kt2 + ksp;
          bf16x8 v0 = *(const bf16x8*)(Vb + SWZ(qc,      2 * ks + hi));
          bf16x8 v1 = *(const bf16x8*)(Vb + SWZ(32 + qc, 2 * ks + hi));
          o0 = __builtin_amdgcn_mfma_f32_32x32x16_bf16(U.v, v0, o0, 0, 0, 0);
          o1 = __builtin_amdgcn_mfma_f32_32x32x16_bf16(U.v, v1, o1, 0, 0, 0);
        }
    }
    cur ^= 1;
  }
  // normalize + store; O row = q = (r&3)+8*(r>>2)+4*hi, col d = qc (+32)
  if (hi == 0) Sc[w][qc] = 1.0f / lrun;
  #pragma unroll
  for (int r = 0; r < 16; r++) {
    int q = (r & 3) + 8 * (r >> 2) + 4 * hi;
    float il = Sc[w][q];
    size_t base = ((size_t)(b * T_ + wq0 + q) * NH_ + h) * 64;
    ao[base + qc]      = f2bf(o0[r] * il);
    ao[base + 32 + qc] = f2bf(o1[r] * il);
  }
}

// ---------------------------------------------------------------------------
extern "C" void kernel_launch(void* const* d_in, const int* in_sizes, int n_in,
                              void* d_out, int out_size, void* d_ws, size_t ws_size,
                              hipStream_t stream) {
  const float* x    = (const float*)d_in[0];
  const float* x0   = (const float*)d_in[1];
  const float* ve   = (const float*)d_in[2];
  const float* cosp = (const float*)d_in[3];
  const float* sinp = (const float*)d_in[4];
  const float* Wq   = (const float*)d_in[5];
  const float* Wk   = (const float*)d_in[6];
  const float* Wv   = (const float*)d_in[7];
  const float* Wo   = (const float*)d_in[8];
  float* out = (float*)d_out;

  u16* ws = (u16*)d_ws;
  size_t off = 0;
  u16* xbf  = ws + off; off += (size_t)M_ * C_;       // also ao
  u16* xmbf = ws + off; off += (size_t)M_ * C_;       // also Qh
  u16* Wqb  = ws + off; off += (size_t)1024 * 1024;   // also Kh
  u16* Wkb  = ws + off; off += (size_t)256 * 1024;
  u16* Wvb  = ws + off; off += (size_t)256 * 1024;
  u16* Wob  = ws + off; off += (size_t)1024 * 1024;
  u16* qpre = ws + off; off += (size_t)M_ * 1024;
  u16* kpre = ws + off; off += (size_t)M_ * 256;
  u16* vmid = ws + off; off += (size_t)M_ * 256;
  u16* VtG  = ws + off; off += (size_t)B_ * NKV_ * 64 * T_;
  u16* aob = xbf;
  u16* Qhb = xmbf;
  u16* Khb = Wqb;

  k_convert_all<<<2560, 256, 0, stream>>>(Wq, Wk, Wv, Wo, Wqb);
  k_rms_combine<<<4096, 256, 0, stream>>>(x, x0, xbf, xmbf);
  k_gemm_qkv<<<dim3(32, 28), 256, 0, stream>>>(xmbf, xbf, Wqb, Wkb, Wvb,
                                               qpre, kpre, vmid, out + (size_t)M_ * C_);
  k_qk_post<<<20480, 256, 0, stream>>>(qpre, kpre, cosp, sinp, Qhb, Khb);
  k_vt<<<dim3(32, 4, 2), 256, 0, stream>>>(vmid, ve, VtG);
  k_attn<<<dim3(8, 16, 2), 512, 0, stream>>>(Qhb, Khb, VtG, aob);
  k_gemm_o<<<dim3(32, 16), 256, 0, stream>>>(aob, Wob, out);
}